// Round 11
// baseline (748.744 us; speedup 1.0000x reference)
//
#include <hip/hip_runtime.h>
#include <hip/hip_cooperative_groups.h>
#include <cstdint>
#include <cstddef>

namespace cg = cooperative_groups;

#define S_TOK 8192
#define DIM   2048
#define NE    64
#define CAP   128
#define KSPLIT 4
#define BS    64   // tokens per GEMM block
#define DT    32   // D-tile per GEMM iteration
#define XW    36   // xs row stride (floats): 144B, 16B-aligned
#define WW    68   // wshT row stride (floats): 272B, 16B-aligned

// output: [0]=l_aux, combine [S,NE,CAP], dispatch [S,NE,CAP]. 134,217,729 floats.
#define NOUT4 33554432ULL   // float4 count covering floats [0, 134217728)
#define DSTRIDE ((size_t)S_TOK * NE * CAP)

// ---- workspace layout (float/int32 units) ----
#define OFF_PART   0              // [KSPLIT][S_TOK][NE] = 2,097,152
#define OFF_IDX    2097152        // [S_TOK] int
#define OFF_GATE   2105344        // [S_TOK] float
#define OFF_MEPART 2121728        // [512][NE] float
#define OFF_PROD   2154496        // (unused)

// ================= shared phase bodies (device functions) =================

__device__ __forceinline__ void phaseA_gemm_zero(
    const float* __restrict__ x, const float* __restrict__ wg,
    float* __restrict__ part, float* __restrict__ out,
    int bid, int tid, float (*xs)[XW], float (*wshT)[WW])
{
    const int k   = bid >> 7;                 // 0..3
    const int sb  = (bid & 127) * BS;
    const int d0  = k * (DIM / KSPLIT);

    const int r  = tid >> 3;                  // 0..31
    const int c  = (tid & 7) * 4;             // 0..28
    const int ti = tid >> 4;                  // 0..15
    const int ei = tid & 15;                  // 0..15

    float4* outv = reinterpret_cast<float4*>(out);
    const size_t zbase = (size_t)bid * 65536 + tid;
    const float4 z4 = make_float4(0.f, 0.f, 0.f, 0.f);

    float4 acc4[4];
    #pragma unroll
    for (int i = 0; i < 4; ++i) acc4[i] = z4;

    int it = 0;
    for (int t = 0; t < DIM / KSPLIT; t += DT, ++it) {
        {
            const float4 xa = *reinterpret_cast<const float4*>(
                &x[(size_t)(sb + r) * DIM + d0 + t + c]);
            const float4 xb = *reinterpret_cast<const float4*>(
                &x[(size_t)(sb + r + 32) * DIM + d0 + t + c]);
            *reinterpret_cast<float4*>(&xs[r][c])      = xa;
            *reinterpret_cast<float4*>(&xs[r + 32][c]) = xb;
        }
        {
            const float4 w0 = *reinterpret_cast<const float4*>(
                &wg[(size_t)r * DIM + d0 + t + c]);
            const float4 w1 = *reinterpret_cast<const float4*>(
                &wg[(size_t)(r + 32) * DIM + d0 + t + c]);
            wshT[c + 0][r] = w0.x; wshT[c + 1][r] = w0.y;
            wshT[c + 2][r] = w0.z; wshT[c + 3][r] = w0.w;
            wshT[c + 0][r + 32] = w1.x; wshT[c + 1][r + 32] = w1.y;
            wshT[c + 2][r + 32] = w1.z; wshT[c + 3][r + 32] = w1.w;
        }
        __syncthreads();

        // fire-and-forget coalesced zero stores (16 float4/thread/iter)
        #pragma unroll
        for (int j = 0; j < 16; ++j)
            outv[zbase + (size_t)(it * 16 + j) * 256] = z4;

        #pragma unroll
        for (int dq = 0; dq < DT / 4; ++dq) {
            float4 xv[4], wv[4];
            #pragma unroll
            for (int i = 0; i < 4; ++i)
                xv[i] = *reinterpret_cast<const float4*>(&xs[ti * 4 + i][dq * 4]);
            #pragma unroll
            for (int q = 0; q < 4; ++q)
                wv[q] = *reinterpret_cast<const float4*>(&wshT[dq * 4 + q][ei * 4]);
            #pragma unroll
            for (int i = 0; i < 4; ++i) {
                acc4[i].x += xv[i].x*wv[0].x + xv[i].y*wv[1].x + xv[i].z*wv[2].x + xv[i].w*wv[3].x;
                acc4[i].y += xv[i].x*wv[0].y + xv[i].y*wv[1].y + xv[i].z*wv[2].y + xv[i].w*wv[3].y;
                acc4[i].z += xv[i].x*wv[0].z + xv[i].y*wv[1].z + xv[i].z*wv[2].z + xv[i].w*wv[3].z;
                acc4[i].w += xv[i].x*wv[0].w + xv[i].y*wv[1].w + xv[i].z*wv[2].w + xv[i].w*wv[3].w;
            }
        }
        __syncthreads();
    }
    if (bid == 511 && tid == 255) out[4ULL * NOUT4] = 0.f;   // odd tail float

    #pragma unroll
    for (int i = 0; i < 4; ++i)
        *reinterpret_cast<float4*>(
            &part[((size_t)k * S_TOK + sb + ti * 4 + i) * NE + ei * 4]) = acc4[i];
}

__device__ __forceinline__ void phaseB_softmax(
    const float* __restrict__ part, int* __restrict__ idx,
    float* __restrict__ gate, float* __restrict__ me_part,
    int gw, int lane, int nwave)
{
    float me_acc = 0.f;
    for (int s = gw; s < S_TOK; s += nwave) {
        float l = 0.f;
        #pragma unroll
        for (int k = 0; k < KSPLIT; ++k)
            l += part[((size_t)k * S_TOK + s) * NE + lane];
        float m = l;
        #pragma unroll
        for (int o = 32; o; o >>= 1) m = fmaxf(m, __shfl_xor(m, o));
        const float ex = __expf(l - m);
        float sum = ex;
        #pragma unroll
        for (int o = 32; o; o >>= 1) sum += __shfl_xor(sum, o);
        float bv = l; int bi = lane;
        #pragma unroll
        for (int o = 32; o; o >>= 1) {
            const float ov = __shfl_xor(bv, o);
            const int   oi = __shfl_xor(bi, o);
            if (ov > bv || (ov == bv && oi < bi)) { bv = ov; bi = oi; }
        }
        const float g = ex / sum;
        me_acc += g;
        if (lane == bi) {
            idx[s]  = bi;
            gate[s] = g;
        }
    }
    me_part[(size_t)gw * NE + lane] = me_acc;
}

__device__ __forceinline__ void phaseC_scan_scatter(
    const int* __restrict__ idx, const float* __restrict__ me_part,
    const float* __restrict__ gate, float* __restrict__ out,
    int e, int tid, int lane, int wid, int* wsum, float* redf)
{
    float mp = me_part[(size_t)tid * NE + e] + me_part[(size_t)(tid + 256) * NE + e];
    #pragma unroll
    for (int o = 32; o; o >>= 1) mp += __shfl_xor(mp, o);
    if (lane == 0) redf[wid] = mp;

    int running = 0;
    for (int c = 0; c < S_TOK; c += 256) {
        const int s = c + tid;
        const bool match = (idx[s] == e);
        const unsigned long long b = __ballot(match);
        const int before = __popcll(b & ((1ULL << lane) - 1ULL));
        if (lane == 0) wsum[wid] = __popcll(b);
        __syncthreads();
        int woff = 0;
        #pragma unroll
        for (int w = 0; w < 4; ++w) if (w < wid) woff += wsum[w];
        const int tot = wsum[0] + wsum[1] + wsum[2] + wsum[3];
        if (match) {
            const int pos = running + woff + before;
            if (pos < CAP) {
                const size_t off = ((size_t)s * NE + e) * CAP + pos;
                out[1 + off] = gate[s];
                out[1 + DSTRIDE + off] = 1.0f;
            }
        }
        running += tot;
        __syncthreads();
    }
    if (tid == 0) {
        const float me = (redf[0] + redf[1] + redf[2] + redf[3]) / (float)S_TOK;
        const float ce = (float)running / (float)S_TOK;
        atomicAdd(&out[0], me * ce * (float)NE);   // sum_e(me*ce)*E == mean*E*E
    }
}

// ================= cooperative fused kernel (512 blocks) =================

__global__ __launch_bounds__(256) void moe_gate_coop(
    const float* __restrict__ x, const float* __restrict__ wg,
    float* __restrict__ part, int* __restrict__ idx,
    float* __restrict__ gate, float* __restrict__ me_part,
    float* __restrict__ out)
{
    cg::grid_group grid = cg::this_grid();

    __shared__ float xs[BS][XW];
    __shared__ float wshT[DT][WW];
    __shared__ int   wsum[4];
    __shared__ float redf[4];

    const int bid  = blockIdx.x;
    const int tid  = threadIdx.x;
    const int lane = tid & 63;
    const int wid  = tid >> 6;

    phaseA_gemm_zero(x, wg, part, out, bid, tid, xs, wshT);
    grid.sync();
    // 512 waves do softmax (waves of blocks 0..127), matching fallback layout
    if (bid < 128)
        phaseB_softmax(part, idx, gate, me_part, bid * 4 + wid, lane, 512);
    grid.sync();
    if (bid < NE)
        phaseC_scan_scatter(idx, me_part, gate, out, bid, tid, lane, wid, wsum, redf);
}

// ================= fallback kernels (proven round-10 path) =================

__global__ __launch_bounds__(256) void gemm_zero(
    const float* __restrict__ x, const float* __restrict__ wg,
    float* __restrict__ part, float* __restrict__ out)
{
    __shared__ float xs[BS][XW];
    __shared__ float wshT[DT][WW];
    const int bid = blockIdx.y * (S_TOK / BS) + blockIdx.x;
    phaseA_gemm_zero(x, wg, part, out, bid, threadIdx.x, xs, wshT);
}

__global__ __launch_bounds__(256) void softmax_top1(
    const float* __restrict__ part, int* __restrict__ idx,
    float* __restrict__ gate, float* __restrict__ me_part)
{
    const int lane = threadIdx.x & 63;
    const int wid  = threadIdx.x >> 6;
    phaseB_softmax(part, idx, gate, me_part, blockIdx.x * 4 + wid, lane, 512);
}

__global__ __launch_bounds__(256) void scan_scatter(
    const int* __restrict__ idx, const float* __restrict__ me_part,
    const float* __restrict__ gate, float* __restrict__ out)
{
    __shared__ int   wsum[4];
    __shared__ float redf[4];
    const int tid = threadIdx.x;
    phaseC_scan_scatter(idx, me_part, gate, out, blockIdx.x,
                        tid, tid & 63, tid >> 6, wsum, redf);
}

extern "C" void kernel_launch(void* const* d_in, const int* in_sizes, int n_in,
                              void* d_out, int out_size, void* d_ws, size_t ws_size,
                              hipStream_t stream)
{
    const float* x  = (const float*)d_in[0];
    const float* wg = (const float*)d_in[1];
    float* out = (float*)d_out;
    float* ws  = (float*)d_ws;

    float* part    = ws + OFF_PART;
    int*   idx     = (int*)(ws + OFF_IDX);
    float* gate    = ws + OFF_GATE;
    float* me_part = ws + OFF_MEPART;

    void* args[] = { (void*)&x, (void*)&wg, (void*)&part, (void*)&idx,
                     (void*)&gate, (void*)&me_part, (void*)&out };
    hipError_t err = hipLaunchCooperativeKernel((const void*)moe_gate_coop,
                                                dim3(512), dim3(256), args, 0, stream);
    if (err != hipSuccess) {
        // proven 3-kernel path (round 10): identical math, same workspace
        dim3 ggrid(S_TOK / BS, KSPLIT);
        gemm_zero<<<ggrid, 256, 0, stream>>>(x, wg, part, out);
        softmax_top1<<<128, 256, 0, stream>>>(part, idx, gate, me_part);
        scan_scatter<<<NE, 256, 0, stream>>>(idx, me_part, gate, out);
    }
}

// Round 12
// 629.597 us; speedup vs baseline: 1.1892x; 1.1892x over previous
//
#include <hip/hip_runtime.h>
#include <cstdint>
#include <cstddef>

#define S_TOK 8192
#define DIM   2048
#define NE    64
#define CAP   128
#define KSPLIT 4
#define BS    64   // tokens per GEMM block
#define DT    32   // D-tile per GEMM iteration
#define XW    36   // xs row stride (floats): 144B, 16B-aligned
#define WW    68   // wshT row stride (floats): 272B, 16B-aligned

// output: [0]=l_aux, combine [S,NE,CAP], dispatch [S,NE,CAP]. 134,217,729 floats.
#define NOUT4 33554432ULL   // float4 count covering floats [0, 134217728)
#define DSTRIDE ((size_t)S_TOK * NE * CAP)

// ---- workspace layout (float/int32 units) ----
#define OFF_PART   0              // [KSPLIT][S_TOK][NE] = 2,097,152
#define OFF_IDX    2097152        // [S_TOK] int
#define OFF_GATE   2105344        // [S_TOK] float
#define OFF_MEPART 2121728        // [512][NE] float

// ---- GEMM (split-K, 4x4 reg tile) + interleaved zeroing of the 537MB output ----
// Write-bound by design: the 33.5MB/iter zero-store stream is the HBM floor the
// whole problem owes; FMA + LDS traffic hide beneath its drain.
__global__ __launch_bounds__(256) void gemm_zero(
    const float* __restrict__ x, const float* __restrict__ wg,
    float* __restrict__ part, float* __restrict__ out)
{
    __shared__ float xs[BS][XW];     // x tile [token][d]
    __shared__ float wshT[DT][WW];   // w tile transposed [d][expert]

    const int sb  = blockIdx.x * BS;
    const int k   = blockIdx.y;
    const int d0  = k * (DIM / KSPLIT);
    const int tid = threadIdx.x;
    const int bid = blockIdx.y * (S_TOK / BS) + blockIdx.x;   // 0..511

    const int r = tid >> 3;          // 0..31
    const int c = (tid & 7) * 4;     // 0..28
    const int ti = tid >> 4;         // 0..15
    const int ei = tid & 15;         // 0..15

    float4* outv = reinterpret_cast<float4*>(out);
    const size_t zbase = (size_t)bid * 65536 + tid;
    const float4 z4 = make_float4(0.f, 0.f, 0.f, 0.f);

    float4 acc4[4];
    #pragma unroll
    for (int i = 0; i < 4; ++i) acc4[i] = z4;

    int it = 0;
    for (int t = 0; t < DIM / KSPLIT; t += DT, ++it) {
        {
            const float4 xa = *reinterpret_cast<const float4*>(
                &x[(size_t)(sb + r) * DIM + d0 + t + c]);
            const float4 xb = *reinterpret_cast<const float4*>(
                &x[(size_t)(sb + r + 32) * DIM + d0 + t + c]);
            *reinterpret_cast<float4*>(&xs[r][c])      = xa;
            *reinterpret_cast<float4*>(&xs[r + 32][c]) = xb;
        }
        {
            const float4 w0 = *reinterpret_cast<const float4*>(
                &wg[(size_t)r * DIM + d0 + t + c]);
            const float4 w1 = *reinterpret_cast<const float4*>(
                &wg[(size_t)(r + 32) * DIM + d0 + t + c]);
            wshT[c + 0][r] = w0.x; wshT[c + 1][r] = w0.y;
            wshT[c + 2][r] = w0.z; wshT[c + 3][r] = w0.w;
            wshT[c + 0][r + 32] = w1.x; wshT[c + 1][r + 32] = w1.y;
            wshT[c + 2][r + 32] = w1.z; wshT[c + 3][r + 32] = w1.w;
        }
        __syncthreads();

        // fire-and-forget zero stores: 16 float4/thread/iter, coalesced
        #pragma unroll
        for (int j = 0; j < 16; ++j)
            outv[zbase + (size_t)(it * 16 + j) * 256] = z4;

        #pragma unroll
        for (int dq = 0; dq < DT / 4; ++dq) {
            float4 xv[4], wv[4];
            #pragma unroll
            for (int i = 0; i < 4; ++i)
                xv[i] = *reinterpret_cast<const float4*>(&xs[ti * 4 + i][dq * 4]);
            #pragma unroll
            for (int q = 0; q < 4; ++q)
                wv[q] = *reinterpret_cast<const float4*>(&wshT[dq * 4 + q][ei * 4]);
            #pragma unroll
            for (int i = 0; i < 4; ++i) {
                acc4[i].x += xv[i].x*wv[0].x + xv[i].y*wv[1].x + xv[i].z*wv[2].x + xv[i].w*wv[3].x;
                acc4[i].y += xv[i].x*wv[0].y + xv[i].y*wv[1].y + xv[i].z*wv[2].y + xv[i].w*wv[3].y;
                acc4[i].z += xv[i].x*wv[0].z + xv[i].y*wv[1].z + xv[i].z*wv[2].z + xv[i].w*wv[3].z;
                acc4[i].w += xv[i].x*wv[0].w + xv[i].y*wv[1].w + xv[i].z*wv[2].w + xv[i].w*wv[3].w;
            }
        }
        __syncthreads();
    }
    // last odd float of the output (float index 134,217,728)
    if (bid == 511 && tid == 255) out[4ULL * NOUT4] = 0.f;

    #pragma unroll
    for (int i = 0; i < 4; ++i)
        *reinterpret_cast<float4*>(
            &part[((size_t)k * S_TOK + sb + ti * 4 + i) * NE + ei * 4]) = acc4[i];
}

// ------- softmax + argmax per token (wave = token, lane = expert), no atomics -------
__global__ __launch_bounds__(256) void softmax_top1(
    const float* __restrict__ part, int* __restrict__ idx,
    float* __restrict__ gate, float* __restrict__ me_part)
{
    const int lane = threadIdx.x & 63;
    const int wid  = threadIdx.x >> 6;
    const int gw   = blockIdx.x * 4 + wid;    // 0..511

    float me_acc = 0.f;
    for (int s = gw; s < S_TOK; s += 512) {
        float l = 0.f;
        #pragma unroll
        for (int k = 0; k < KSPLIT; ++k)
            l += part[((size_t)k * S_TOK + s) * NE + lane];
        float m = l;
        #pragma unroll
        for (int o = 32; o; o >>= 1) m = fmaxf(m, __shfl_xor(m, o));
        const float ex = __expf(l - m);
        float sum = ex;
        #pragma unroll
        for (int o = 32; o; o >>= 1) sum += __shfl_xor(sum, o);
        float bv = l; int bi = lane;
        #pragma unroll
        for (int o = 32; o; o >>= 1) {
            const float ov = __shfl_xor(bv, o);
            const int   oi = __shfl_xor(bi, o);
            if (ov > bv || (ov == bv && oi < bi)) { bv = ov; bi = oi; }
        }
        const float g = ex / sum;
        me_acc += g;
        if (lane == bi) {
            idx[s]  = bi;
            gate[s] = g;
        }
    }
    me_part[(size_t)gw * NE + lane] = me_acc;
}

// --- per-expert capacity scan + INLINE sparse scatter + l_aux atomic (1 block/expert) ---
__global__ __launch_bounds__(256) void scan_scatter(
    const int* __restrict__ idx, const float* __restrict__ me_part,
    const float* __restrict__ gate, float* __restrict__ out)
{
    const int e    = blockIdx.x;
    const int tid  = threadIdx.x;
    const int lane = tid & 63;
    const int wid  = tid >> 6;
    __shared__ int   wsum[4];
    __shared__ float redf[4];

    // reduce me_part[:, e] over 512 waves
    float mp = me_part[(size_t)tid * NE + e] + me_part[(size_t)(tid + 256) * NE + e];
    #pragma unroll
    for (int o = 32; o; o >>= 1) mp += __shfl_xor(mp, o);
    if (lane == 0) redf[wid] = mp;

    int running = 0;
    for (int c = 0; c < S_TOK; c += 256) {
        const int s = c + tid;
        const bool match = (idx[s] == e);
        const unsigned long long b = __ballot(match);
        const int before = __popcll(b & ((1ULL << lane) - 1ULL));
        if (lane == 0) wsum[wid] = __popcll(b);
        __syncthreads();
        int woff = 0;
        #pragma unroll
        for (int w = 0; w < 4; ++w) if (w < wid) woff += wsum[w];
        const int tot = wsum[0] + wsum[1] + wsum[2] + wsum[3];
        if (match) {
            const int pos = running + woff + before;
            if (pos < CAP) {   // scatter directly (output pre-zeroed by gemm_zero)
                const size_t off = ((size_t)s * NE + e) * CAP + pos;
                out[1 + off] = gate[s];
                out[1 + DSTRIDE + off] = 1.0f;
            }
        }
        running += tot;
        __syncthreads();
    }
    if (tid == 0) {
        const float me = (redf[0] + redf[1] + redf[2] + redf[3]) / (float)S_TOK;
        const float ce = (float)running / (float)S_TOK;
        // l_aux = mean_e(me*ce)*E*E = sum_e(me*ce)*E ; out[0] zeroed by gemm_zero
        atomicAdd(&out[0], me * ce * (float)NE);
    }
}

extern "C" void kernel_launch(void* const* d_in, const int* in_sizes, int n_in,
                              void* d_out, int out_size, void* d_ws, size_t ws_size,
                              hipStream_t stream)
{
    const float* x  = (const float*)d_in[0];
    const float* wg = (const float*)d_in[1];
    float* out = (float*)d_out;
    float* ws  = (float*)d_ws;

    float* part    = ws + OFF_PART;
    int*   idx     = (int*)(ws + OFF_IDX);
    float* gate    = ws + OFF_GATE;
    float* me_part = ws + OFF_MEPART;

    dim3 ggrid(S_TOK / BS, KSPLIT);
    gemm_zero<<<ggrid, 256, 0, stream>>>(x, wg, part, out);
    softmax_top1<<<128, 256, 0, stream>>>(part, idx, gate, me_part);
    scan_scatter<<<NE, 256, 0, stream>>>(idx, me_part, gate, out);
}